// Round 2
// baseline (1042.885 us; speedup 1.0000x reference)
//
#include <hip/hip_runtime.h>
#include <math.h>

#define NTOK 16384
#define DIM  4096
#define NE   64
#define TOPK 8
#define TPW  8             // tokens per wave
#define WPB  4             // waves per block (256 threads)
#define ROUTE_SCALE 2.5f

__global__ __launch_bounds__(256, 2)
void router_kernel(const float* __restrict__ x,
                   const float* __restrict__ gw,
                   const float* __restrict__ bias,
                   float* __restrict__ out)
{
    __shared__ int hist_lds[NE];

    const int t    = threadIdx.x;
    const int lane = t & 63;                                   // lane == expert
    const int wid  = __builtin_amdgcn_readfirstlane(t >> 6);   // force wave-uniform

    if (t < NE) hist_lds[t] = 0;
    __syncthreads();

    const int tok0 = blockIdx.x * (WPB * TPW) + wid * TPW;
    const float* wrow = gw + (size_t)lane * DIM;

    float acc[TPW];
#pragma unroll
    for (int i = 0; i < TPW; ++i) acc[i] = 0.f;

    // w chunk double buffer: 2 x 64 VGPRs, statically indexed (named A/B)
    float wA[64], wB[64];

#define LOAD_W(buf, cc)                                              \
    _Pragma("unroll")                                                \
    for (int i = 0; i < 16; ++i)                                     \
        *(float4*)&buf[i * 4] = *(const float4*)&wrow[(cc) + i * 4];

#define FMA_CHUNK(buf, cc)                                           \
    _Pragma("unroll")                                                \
    for (int tt = 0; tt < TPW; ++tt) {                               \
        const float* xrow = x + (size_t)(tok0 + tt) * DIM + (cc);    \
        _Pragma("unroll")                                            \
        for (int d = 0; d < 64; ++d)                                 \
            acc[tt] = fmaf(xrow[d], buf[d], acc[tt]);                \
    }

    LOAD_W(wA, 0);
    for (int c = 0; c < DIM; c += 128) {
        LOAD_W(wB, c + 64);
        FMA_CHUNK(wA, c);
        if (c + 128 < DIM) { LOAD_W(wA, c + 128); }
        FMA_CHUNK(wB, c + 64);
    }

    // ---- epilogue: sigmoid, biased top-8 across lanes, normalize, hist ----
    const float b = bias[lane];
    float sc[TPW], biased[TPW];
#pragma unroll
    for (int tt = 0; tt < TPW; ++tt) {
        sc[tt]     = 1.f / (1.f + expf(-acc[tt]));
        biased[tt] = sc[tt] + b;
    }

#pragma unroll
    for (int tt = 0; tt < TPW; ++tt) {
        float myv  = biased[tt];
        float outv = 0.f;
        int   outi = 0;
        float sum  = 0.f;
#pragma unroll
        for (int k = 0; k < TOPK; ++k) {
            float cv = myv;
            int   ci = lane;
#pragma unroll
            for (int off = 32; off; off >>= 1) {
                float ov = __shfl_xor(cv, off, 64);
                int   oi = __shfl_xor(ci, off, 64);
                if (ov > cv || (ov == cv && oi < ci)) { cv = ov; ci = oi; }
            }
            // ci = argmax expert this round (identical across lanes)
            float ts = __shfl(sc[tt], ci, 64);   // unbiased score of winner
            sum += ts;
            if (lane == k)  { outv = ts; outi = ci; }
            if (lane == ci) { myv = -1e30f; }    // remove winner
        }
        const float denom = sum + 1e-20f;
        const size_t tok  = (size_t)tok0 + tt;
        if (lane < TOPK) {
            out[tok * TOPK + lane] = (outv / denom) * ROUTE_SCALE;
            out[(size_t)NTOK * TOPK + tok * TOPK + lane] = (float)outi;
            atomicAdd(&hist_lds[outi], 1);
        }
    }

    __syncthreads();
    if (t < NE) {
        int c = hist_lds[t];
        if (c) atomicAdd(&out[(size_t)NTOK * TOPK * 2 + t], (float)c);
    }
}

extern "C" void kernel_launch(void* const* d_in, const int* in_sizes, int n_in,
                              void* d_out, int out_size, void* d_ws, size_t ws_size,
                              hipStream_t stream)
{
    const float* x    = (const float*)d_in[0];
    const float* gw   = (const float*)d_in[1];
    const float* bias = (const float*)d_in[2];
    float* out = (float*)d_out;

    // histogram region must start at zero every call (atomics accumulate into it)
    hipMemsetAsync(out + (size_t)NTOK * TOPK * 2, 0, NE * sizeof(float), stream);

    router_kernel<<<NTOK / (WPB * TPW), 256, 0, stream>>>(x, gw, bias, out);
}

// Round 3
// 314.984 us; speedup vs baseline: 3.3109x; 3.3109x over previous
//
#include <hip/hip_runtime.h>
#include <math.h>

#define NTOK 16384
#define DIM  4096
#define NE   64
#define TOPK 8
#define KC   64            // k-chunk
#define NT   (DIM / KC)    // 64 chunks
#define XSTR 66            // x tile row stride in floats: 66 ≡ 2 (mod 32) -> b64 reads 4-way max
#define ROUTE_SCALE 2.5f

// ---------------- w transpose: gw[e][k] -> wT[k][e] (in d_ws) ----------------
__global__ __launch_bounds__(256, 2)
void transpose_w(const float* __restrict__ gw, float* __restrict__ wT)
{
    __shared__ float tile[64][68];
    const int t  = threadIdx.x;
    const int k0 = blockIdx.x * 64;

    const int e = t >> 2, c = (t & 3) * 16;
#pragma unroll
    for (int i = 0; i < 4; ++i) {
        float4 v = *(const float4*)&gw[(size_t)e * DIM + k0 + c + i * 4];
        *(float4*)&tile[e][c + i * 4] = v;
    }
    __syncthreads();
    const int k = t >> 2, ce = (t & 3) * 16;
    float o[16];
#pragma unroll
    for (int i = 0; i < 16; ++i) o[i] = tile[ce + i][k];
#pragma unroll
    for (int i = 0; i < 4; ++i)
        *(float4*)&wT[(size_t)(k0 + k) * NE + ce + i * 4] = *(float4*)&o[i * 4];
}

// ---------------- main: GEMM + sigmoid + top-8 + histogram ----------------
__global__ __launch_bounds__(512, 1)
void router_kernel(const float* __restrict__ x,
                   const float* __restrict__ wT,
                   const float* __restrict__ bias,
                   float* __restrict__ out)
{
    __shared__ float xs[2][64][XSTR];
    __shared__ float sc[64][NE + 1];
    __shared__ int   hist[NE];

    const int t    = threadIdx.x;
    const int lane = t & 63;                                   // lane == token-within-group
    const int wv   = __builtin_amdgcn_readfirstlane(t >> 6);   // wave 0..7, force uniform
    const int e0   = wv * 8;                                   // this wave's expert slice
    const int tok0 = blockIdx.x * 64;

    if (t < NE) hist[t] = 0;

    // staging map: thread -> (row, 16B col); wave covers 8 rows x 128B contiguous
    const int sr  = t >> 3;
    const int sc0 = (t & 7) * 4;
    const float* xg = x + (size_t)(tok0 + sr) * DIM;

    float acc[8];
#pragma unroll
    for (int i = 0; i < 8; ++i) acc[i] = 0.f;

    // prologue: chunk0 -> xs[0]; chunk1 -> regs
    float4 pA = *(const float4*)&xg[sc0];
    float4 pB = *(const float4*)&xg[sc0 + 32];
    *(float2*)&xs[0][sr][sc0]      = make_float2(pA.x, pA.y);
    *(float2*)&xs[0][sr][sc0 + 2]  = make_float2(pA.z, pA.w);
    *(float2*)&xs[0][sr][sc0 + 32] = make_float2(pB.x, pB.y);
    *(float2*)&xs[0][sr][sc0 + 34] = make_float2(pB.z, pB.w);
    pA = *(const float4*)&xg[KC + sc0];
    pB = *(const float4*)&xg[KC + sc0 + 32];

    for (int tch = 0; tch < NT; ++tch) {
        const int cur = tch & 1;
        __syncthreads();   // all writes to xs[cur] done; all reads of xs[cur^1] done
        if (tch + 1 < NT) {
            const int nxt = cur ^ 1;
            *(float2*)&xs[nxt][sr][sc0]      = make_float2(pA.x, pA.y);
            *(float2*)&xs[nxt][sr][sc0 + 2]  = make_float2(pA.z, pA.w);
            *(float2*)&xs[nxt][sr][sc0 + 32] = make_float2(pB.x, pB.y);
            *(float2*)&xs[nxt][sr][sc0 + 34] = make_float2(pB.z, pB.w);
            if (tch + 2 < NT) {
                pA = *(const float4*)&xg[(tch + 2) * KC + sc0];
                pB = *(const float4*)&xg[(tch + 2) * KC + sc0 + 32];
            }
        }
        // compute chunk tch: k strictly sequential -> bit-identical logits
        const float* wrow = wT + (size_t)tch * KC * NE + e0;   // uniform address
#pragma unroll
        for (int kp = 0; kp < KC / 4; ++kp) {
            const float2 xa = *(const float2*)&xs[cur][lane][kp * 4];
            const float2 xb = *(const float2*)&xs[cur][lane][kp * 4 + 2];
#pragma unroll
            for (int kk = 0; kk < 4; ++kk) {
                const float4 wlo = *(const float4*)(wrow + (size_t)(kp * 4 + kk) * NE);
                const float4 whi = *(const float4*)(wrow + (size_t)(kp * 4 + kk) * NE + 4);
                const float xk = (kk == 0) ? xa.x : (kk == 1) ? xa.y : (kk == 2) ? xb.x : xb.y;
                acc[0] = fmaf(xk, wlo.x, acc[0]);
                acc[1] = fmaf(xk, wlo.y, acc[1]);
                acc[2] = fmaf(xk, wlo.z, acc[2]);
                acc[3] = fmaf(xk, wlo.w, acc[3]);
                acc[4] = fmaf(xk, whi.x, acc[4]);
                acc[5] = fmaf(xk, whi.y, acc[5]);
                acc[6] = fmaf(xk, whi.z, acc[6]);
                acc[7] = fmaf(xk, whi.w, acc[7]);
            }
        }
    }

    // sigmoid -> score matrix
    __syncthreads();
#pragma unroll
    for (int i = 0; i < 8; ++i)
        sc[lane][e0 + i] = 1.f / (1.f + expf(-acc[i]));
    __syncthreads();

    // top-8: wave wv handles tokens wv*8 .. wv*8+7; lane == expert
    const float bias_l = bias[lane];
#pragma unroll 1
    for (int i = 0; i < 8; ++i) {
        const int tok = wv * 8 + i;
        const float s = sc[tok][lane];
        float myv = s + bias_l;
        float outv = 0.f;
        int   outi = 0;
        float sum  = 0.f;
#pragma unroll
        for (int k = 0; k < TOPK; ++k) {
            float cv = myv;
            int   ci = lane;
#pragma unroll
            for (int off = 32; off; off >>= 1) {
                float ov = __shfl_xor(cv, off, 64);
                int   oi = __shfl_xor(ci, off, 64);
                if (ov > cv || (ov == cv && oi < ci)) { cv = ov; ci = oi; }
            }
            float ts = __shfl(s, ci, 64);   // unbiased score of winner
            sum += ts;
            if (lane == k)  { outv = ts; outi = ci; }
            if (lane == ci) { myv = -1e30f; }
        }
        const float denom = sum + 1e-20f;
        const size_t gt = (size_t)tok0 + tok;
        if (lane < TOPK) {
            out[gt * TOPK + lane] = (outv / denom) * ROUTE_SCALE;
            out[(size_t)NTOK * TOPK + gt * TOPK + lane] = (float)outi;
            atomicAdd(&hist[outi], 1);
        }
    }

    __syncthreads();
    if (t < NE) {
        int c = hist[t];
        if (c) atomicAdd(&out[(size_t)NTOK * TOPK * 2 + t], (float)c);
    }
}

extern "C" void kernel_launch(void* const* d_in, const int* in_sizes, int n_in,
                              void* d_out, int out_size, void* d_ws, size_t ws_size,
                              hipStream_t stream)
{
    const float* x    = (const float*)d_in[0];
    const float* gw   = (const float*)d_in[1];
    const float* bias = (const float*)d_in[2];
    float* out = (float*)d_out;
    float* wT  = (float*)d_ws;   // needs DIM*NE*4 = 1 MB

    hipMemsetAsync(out + (size_t)NTOK * TOPK * 2, 0, NE * sizeof(float), stream);

    transpose_w<<<DIM / 64, 256, 0, stream>>>(gw, wT);
    router_kernel<<<NTOK / 64, 512, 0, stream>>>(x, wT, bias, out);
}

// Round 4
// 151.875 us; speedup vs baseline: 6.8667x; 2.0740x over previous
//
#include <hip/hip_runtime.h>
#include <math.h>

#define NTOK 16384
#define DIM  4096
#define NE   64
#define TOPK 8
#define ROUTE_SCALE 2.5f

typedef __attribute__((ext_vector_type(8))) short short8v;
typedef __attribute__((ext_vector_type(4))) float f32x4;

// d_ws layout: [0, 1.5MB) wS bf16-split w fragments; [2MB, 10MB) split-K partials
#define WS_PART_OFF (2u * 1024u * 1024u)

// exact 3-term bf16 truncation split of 8 f32, packed as 3x short8 (bf16) frags
__device__ __forceinline__ void split3_pack(const float* v, uint4& b0, uint4& b1, uint4& b2)
{
    uint p0[8], p1[8], p2[8];
#pragma unroll
    for (int j = 0; j < 8; ++j) {
        const float xv = v[j];
        const uint  u0 = __float_as_uint(xv) & 0xffff0000u;
        const float f0 = __uint_as_float(u0);
        const float r  = xv - f0;                       // exact
        const uint  u1 = __float_as_uint(r) & 0xffff0000u;
        const float f1 = __uint_as_float(u1);
        const float r2 = r - f1;                        // exact, fits bf16
        const uint  u2 = __float_as_uint(r2) & 0xffff0000u;
        p0[j] = u0; p1[j] = u1; p2[j] = u2;
    }
    b0 = make_uint4(p0[1] | (p0[0] >> 16), p0[3] | (p0[2] >> 16),
                    p0[5] | (p0[4] >> 16), p0[7] | (p0[6] >> 16));
    b1 = make_uint4(p1[1] | (p1[0] >> 16), p1[3] | (p1[2] >> 16),
                    p1[5] | (p1[4] >> 16), p1[7] | (p1[6] >> 16));
    b2 = make_uint4(p2[1] | (p2[0] >> 16), p2[3] | (p2[2] >> 16),
                    p2[5] | (p2[4] >> 16), p2[7] | (p2[6] >> 16));
}

// ---- prep: w -> frag-ready bf16 splits. entry(ks,nt,sp,lane) at ((ks*4+nt)*3+sp)*64+lane
__global__ __launch_bounds__(256)
void prep_w(const float* __restrict__ gw, uint4* __restrict__ wS)
{
    const int tid  = blockIdx.x * 256 + threadIdx.x;   // 32768 total
    const int lane = tid & 63;
    const int nt   = (tid >> 6) & 3;
    const int ks   = tid >> 8;                         // 0..127
    const int e    = nt * 16 + (lane & 15);
    const int kb   = ks * 32 + (lane >> 4) * 8;
    float v[8];
    *(float4*)&v[0] = *(const float4*)&gw[(size_t)e * DIM + kb];
    *(float4*)&v[4] = *(const float4*)&gw[(size_t)e * DIM + kb + 4];
    uint4 b0, b1, b2;
    split3_pack(v, b0, b1, b2);
    const size_t base = (size_t)(ks * 4 + nt) * 3 * 64 + lane;
    wS[base] = b0; wS[base + 64] = b1; wS[base + 128] = b2;
}

// ---- stage 1: 1-wave blocks, 16 tokens/wave, split-K=2, no LDS/barriers ----
__global__ __launch_bounds__(64, 2)
void gemm_stage(const float* __restrict__ x, const uint4* __restrict__ wS,
                float* __restrict__ part)
{
    const int lane = threadIdx.x;
    const int r    = lane & 15;
    const int g    = lane >> 4;
    const int tok0 = blockIdx.x * 16;
    const int kh   = blockIdx.y;               // 0..1

    const float* xr = x + (size_t)(tok0 + r) * DIM + kh * (DIM / 2) + g * 8;
    const uint4* wB = wS + (size_t)kh * 64 * 768 + lane;   // slice stride 768 entries

    f32x4 acc[4];
#pragma unroll
    for (int nt = 0; nt < 4; ++nt) acc[nt] = (f32x4){0.f, 0.f, 0.f, 0.f};

    float4 xP0, xP1, xQ0, xQ1;
    uint4  bP[12], bQ[12];

#define LOADX(X0, X1, s) do {                                     \
        X0 = *(const float4*)(xr + (size_t)(s) * 32);             \
        X1 = *(const float4*)(xr + (size_t)(s) * 32 + 4);         \
    } while (0)
#define LOADB(B, s) do {                                          \
        _Pragma("unroll")                                         \
        for (int i = 0; i < 12; ++i)                              \
            B[i] = wB[(size_t)(s) * 768 + i * 64];                \
    } while (0)
#define COMPUTE(X0, X1, B) do {                                                   \
        float v[8];                                                               \
        *(float4*)&v[0] = X0; *(float4*)&v[4] = X1;                               \
        uint4 a0u, a1u, a2u;                                                      \
        split3_pack(v, a0u, a1u, a2u);                                            \
        const short8v a0 = *(short8v*)&a0u;                                       \
        const short8v a1 = *(short8v*)&a1u;                                       \
        const short8v a2 = *(short8v*)&a2u;                                       \
        _Pragma("unroll")                                                         \
        for (int nt = 0; nt < 4; ++nt) {                                          \
            const short8v b0 = *(const short8v*)&B[nt * 3 + 0];                   \
            const short8v b1 = *(const short8v*)&B[nt * 3 + 1];                   \
            const short8v b2 = *(const short8v*)&B[nt * 3 + 2];                   \
            f32x4 c = acc[nt];                                                    \
            c = __builtin_amdgcn_mfma_f32_16x16x32_bf16(a2, b0, c, 0, 0, 0);      \
            c = __builtin_amdgcn_mfma_f32_16x16x32_bf16(a1, b1, c, 0, 0, 0);      \
            c = __builtin_amdgcn_mfma_f32_16x16x32_bf16(a0, b2, c, 0, 0, 0);      \
            c = __builtin_amdgcn_mfma_f32_16x16x32_bf16(a1, b0, c, 0, 0, 0);      \
            c = __builtin_amdgcn_mfma_f32_16x16x32_bf16(a0, b1, c, 0, 0, 0);      \
            c = __builtin_amdgcn_mfma_f32_16x16x32_bf16(a0, b0, c, 0, 0, 0);      \
            acc[nt] = c;                                                          \
        }                                                                         \
    } while (0)

    LOADX(xP0, xP1, 0);
    LOADB(bP, 0);
    for (int it = 0; it < 32; ++it) {
        const int s = 2 * it;
        LOADX(xQ0, xQ1, s + 1);
        LOADB(bQ, s + 1);
        COMPUTE(xP0, xP1, bP);
        const int s2 = (s + 2) & 63;          // last iter loads slice 0, never used
        LOADX(xP0, xP1, s2);
        LOADB(bP, s2);
        COMPUTE(xQ0, xQ1, bQ);
    }

    // C/D layout (m89-verified): col = lane&15 (expert), row = (lane>>4)*4 + reg (token)
    float* pp = part + (size_t)kh * NTOK * NE;
#pragma unroll
    for (int nt = 0; nt < 4; ++nt)
#pragma unroll
        for (int q = 0; q < 4; ++q) {
            const int token = tok0 + g * 4 + q;
            const int e     = nt * 16 + r;
            pp[(size_t)token * NE + e] = acc[nt][q];
        }
#undef LOADX
#undef LOADB
#undef COMPUTE
}

// ---- stage 2: fixed-order reduce + sigmoid + top-8 + histogram ----
__global__ __launch_bounds__(256)
void epilogue(const float* __restrict__ part, const float* __restrict__ bias,
              float* __restrict__ out)
{
    __shared__ int hist[NE];
    const int t    = threadIdx.x;
    const int lane = t & 63;                                   // lane == expert
    const int wv   = __builtin_amdgcn_readfirstlane(t >> 6);   // 0..3

    if (t < NE) hist[t] = 0;
    __syncthreads();

    const float bias_l = bias[lane];
    const float* p0 = part;
    const float* p1 = part + (size_t)NTOK * NE;

#pragma unroll 1
    for (int i = 0; i < 4; ++i) {
        const int tok = blockIdx.x * 16 + wv * 4 + i;
        const float logit = p0[(size_t)tok * NE + lane] + p1[(size_t)tok * NE + lane];
        const float s = 1.f / (1.f + expf(-logit));
        float myv  = s + bias_l;
        float outv = 0.f;
        int   outi = 0;
        float sum  = 0.f;
#pragma unroll
        for (int k = 0; k < TOPK; ++k) {
            float cv = myv;
            int   ci = lane;
#pragma unroll
            for (int off = 32; off; off >>= 1) {
                float ov = __shfl_xor(cv, off, 64);
                int   oi = __shfl_xor(ci, off, 64);
                if (ov > cv || (ov == cv && oi < ci)) { cv = ov; ci = oi; }
            }
            float ts = __shfl(s, ci, 64);      // unbiased score of winner
            sum += ts;
            if (lane == k)  { outv = ts; outi = ci; }
            if (lane == ci) { myv = -1e30f; }
        }
        const float denom = sum + 1e-20f;
        if (lane < TOPK) {
            out[(size_t)tok * TOPK + lane] = (outv / denom) * ROUTE_SCALE;
            out[(size_t)NTOK * TOPK + (size_t)tok * TOPK + lane] = (float)outi;
            atomicAdd(&hist[outi], 1);
        }
    }

    __syncthreads();
    if (t < NE) {
        int c = hist[t];
        if (c) atomicAdd(&out[(size_t)NTOK * TOPK * 2 + t], (float)c);
    }
}

extern "C" void kernel_launch(void* const* d_in, const int* in_sizes, int n_in,
                              void* d_out, int out_size, void* d_ws, size_t ws_size,
                              hipStream_t stream)
{
    const float* x    = (const float*)d_in[0];
    const float* gw   = (const float*)d_in[1];
    const float* bias = (const float*)d_in[2];
    float* out  = (float*)d_out;
    uint4* wS   = (uint4*)d_ws;
    float* part = (float*)((char*)d_ws + WS_PART_OFF);

    // histogram region must start at zero every call
    hipMemsetAsync(out + (size_t)NTOK * TOPK * 2, 0, NE * sizeof(float), stream);

    prep_w<<<128, 256, 0, stream>>>(gw, wS);
    gemm_stage<<<dim3(NTOK / 16, 2), 64, 0, stream>>>(x, wS, part);
    epilogue<<<NTOK / 16, 256, 0, stream>>>(part, bias, out);
}

// Round 5
// 129.779 us; speedup vs baseline: 8.0359x; 1.1703x over previous
//
#include <hip/hip_runtime.h>
#include <math.h>

#define NTOK 16384
#define DIM  4096
#define NE   64
#define TOPK 8
#define SPLITK 8
#define NSLICE (DIM / SPLITK / 32)   // 16 k32-slices per block
#define ROUTE_SCALE 2.5f

typedef __attribute__((ext_vector_type(8))) short short8v;
typedef __attribute__((ext_vector_type(4))) float f32x4;

// d_ws layout: [0, 1.5MB) wS bf16-split w fragments; [2MB, 34MB) split-K partials
#define WS_PART_OFF (2u * 1024u * 1024u)

// exact 3-term bf16 truncation split of 8 f32, packed as 3x short8 (bf16) frags
__device__ __forceinline__ void split3_pack(const float* v, uint4& b0, uint4& b1, uint4& b2)
{
    uint p0[8], p1[8], p2[8];
#pragma unroll
    for (int j = 0; j < 8; ++j) {
        const float xv = v[j];
        const uint  u0 = __float_as_uint(xv) & 0xffff0000u;
        const float f0 = __uint_as_float(u0);
        const float r  = xv - f0;                       // exact
        const uint  u1 = __float_as_uint(r) & 0xffff0000u;
        const float f1 = __uint_as_float(u1);
        const float r2 = r - f1;                        // exact, fits bf16
        const uint  u2 = __float_as_uint(r2) & 0xffff0000u;
        p0[j] = u0; p1[j] = u1; p2[j] = u2;
    }
    b0 = make_uint4(p0[1] | (p0[0] >> 16), p0[3] | (p0[2] >> 16),
                    p0[5] | (p0[4] >> 16), p0[7] | (p0[6] >> 16));
    b1 = make_uint4(p1[1] | (p1[0] >> 16), p1[3] | (p1[2] >> 16),
                    p1[5] | (p1[4] >> 16), p1[7] | (p1[6] >> 16));
    b2 = make_uint4(p2[1] | (p2[0] >> 16), p2[3] | (p2[2] >> 16),
                    p2[5] | (p2[4] >> 16), p2[7] | (p2[6] >> 16));
}

// ---- prep: w -> frag-ready bf16 splits. entry(ks,nt,sp,lane) at (ks*12 + nt*3+sp)*64+lane
__global__ __launch_bounds__(256)
void prep_w(const float* __restrict__ gw, uint4* __restrict__ wS)
{
    const int tid  = blockIdx.x * 256 + threadIdx.x;   // 32768 total
    const int lane = tid & 63;
    const int nt   = (tid >> 6) & 3;
    const int ks   = tid >> 8;                         // 0..127
    const int e    = nt * 16 + (lane & 15);
    const int kb   = ks * 32 + (lane >> 4) * 8;
    float v[8];
    *(float4*)&v[0] = *(const float4*)&gw[(size_t)e * DIM + kb];
    *(float4*)&v[4] = *(const float4*)&gw[(size_t)e * DIM + kb + 4];
    uint4 b0, b1, b2;
    split3_pack(v, b0, b1, b2);
    const size_t base = (size_t)(ks * 4 + nt) * 3 * 64 + lane;
    wS[base] = b0; wS[base + 64] = b1; wS[base + 128] = b2;
}

// ---- stage 1: 1-wave blocks, 64 tokens/wave (4 groups), split-K=8 ----
__global__ __launch_bounds__(64, 2)
void gemm_stage(const float* __restrict__ x, const uint4* __restrict__ wS,
                float* __restrict__ part)
{
    const int lane = threadIdx.x;
    const int r    = lane & 15;
    const int g    = lane >> 4;
    const int tok0 = blockIdx.x * 64;
    const int kh   = blockIdx.y;               // 0..7
    const int ks0  = kh * NSLICE;              // global k32-slice base

    const float* xr[4];
#pragma unroll
    for (int G = 0; G < 4; ++G)
        xr[G] = x + (size_t)(tok0 + G * 16 + r) * DIM + ks0 * 32 + g * 8;
    const uint4* wB = wS + lane;

    f32x4 acc[16];                              // [nt*4 + G]
#pragma unroll
    for (int i = 0; i < 16; ++i) acc[i] = (f32x4){0.f, 0.f, 0.f, 0.f};

    float xP[32], xQ[32];                       // 4 groups x 8 floats
    uint4 bP[12], bQ[12];

#define LOADX(X, s) do {                                                     \
        _Pragma("unroll")                                                    \
        for (int G = 0; G < 4; ++G) {                                        \
            *(float4*)&X[G * 8]     = *(const float4*)(xr[G] + (size_t)(s) * 32);     \
            *(float4*)&X[G * 8 + 4] = *(const float4*)(xr[G] + (size_t)(s) * 32 + 4); \
        }                                                                    \
    } while (0)
#define LOADB(B, s) do {                                                     \
        _Pragma("unroll")                                                    \
        for (int i = 0; i < 12; ++i)                                         \
            B[i] = wB[((size_t)(ks0 + (s)) * 12 + i) * 64];                  \
    } while (0)
#define COMPUTE(X, B) do {                                                            \
        _Pragma("unroll")                                                             \
        for (int G = 0; G < 4; ++G) {                                                 \
            uint4 a0u, a1u, a2u;                                                      \
            split3_pack(&X[G * 8], a0u, a1u, a2u);                                    \
            const short8v a0 = *(short8v*)&a0u;                                       \
            const short8v a1 = *(short8v*)&a1u;                                       \
            const short8v a2 = *(short8v*)&a2u;                                       \
            _Pragma("unroll")                                                         \
            for (int nt = 0; nt < 4; ++nt) {                                          \
                const short8v b0 = *(const short8v*)&B[nt * 3 + 0];                   \
                const short8v b1 = *(const short8v*)&B[nt * 3 + 1];                   \
                const short8v b2 = *(const short8v*)&B[nt * 3 + 2];                   \
                f32x4 c = acc[nt * 4 + G];                                            \
                c = __builtin_amdgcn_mfma_f32_16x16x32_bf16(a2, b0, c, 0, 0, 0);      \
                c = __builtin_amdgcn_mfma_f32_16x16x32_bf16(a1, b1, c, 0, 0, 0);      \
                c = __builtin_amdgcn_mfma_f32_16x16x32_bf16(a0, b2, c, 0, 0, 0);      \
                c = __builtin_amdgcn_mfma_f32_16x16x32_bf16(a1, b0, c, 0, 0, 0);      \
                c = __builtin_amdgcn_mfma_f32_16x16x32_bf16(a0, b1, c, 0, 0, 0);      \
                c = __builtin_amdgcn_mfma_f32_16x16x32_bf16(a0, b0, c, 0, 0, 0);      \
                acc[nt * 4 + G] = c;                                                  \
            }                                                                         \
        }                                                                             \
    } while (0)

    LOADX(xP, 0);
    LOADB(bP, 0);
    for (int it = 0; it < NSLICE / 2; ++it) {
        const int s = 2 * it;
        LOADX(xQ, s + 1);
        LOADB(bQ, s + 1);
        COMPUTE(xP, bP);
        const int s2 = (s + 2) & (NSLICE - 1);   // last iter wraps to 0, never used
        LOADX(xP, s2);
        LOADB(bP, s2);
        COMPUTE(xQ, bQ);
    }

    // C/D layout (m89-verified, round-4-proven): col = lane&15 (expert), row = g*4+q (token)
    float* pp = part + (size_t)kh * NTOK * NE;
#pragma unroll
    for (int nt = 0; nt < 4; ++nt)
#pragma unroll
        for (int G = 0; G < 4; ++G)
#pragma unroll
            for (int q = 0; q < 4; ++q) {
                const int token = tok0 + G * 16 + g * 4 + q;
                pp[(size_t)token * NE + nt * 16 + r] = acc[nt * 4 + G][q];
            }
#undef LOADX
#undef LOADB
#undef COMPUTE
}

// ---- stage 2: fixed-order reduce + sigmoid + top-8 + histogram ----
__global__ __launch_bounds__(256)
void epilogue(const float* __restrict__ part, const float* __restrict__ bias,
              float* __restrict__ out)
{
    __shared__ int hist[NE];
    const int t    = threadIdx.x;
    const int lane = t & 63;                                   // lane == expert
    const int wv   = __builtin_amdgcn_readfirstlane(t >> 6);   // 0..3

    if (t < NE) hist[t] = 0;
    __syncthreads();

    const float bias_l = bias[lane];

#pragma unroll 1
    for (int i = 0; i < 4; ++i) {
        const int tok = blockIdx.x * 16 + wv * 4 + i;
        float logit = 0.f;
#pragma unroll
        for (int kh = 0; kh < SPLITK; ++kh)     // fixed ascending order: deterministic
            logit += part[(size_t)kh * NTOK * NE + (size_t)tok * NE + lane];
        const float s = 1.f / (1.f + expf(-logit));
        float myv  = s + bias_l;
        float outv = 0.f;
        int   outi = 0;
        float sum  = 0.f;
#pragma unroll
        for (int k = 0; k < TOPK; ++k) {
            float cv = myv;
            int   ci = lane;
#pragma unroll
            for (int off = 32; off; off >>= 1) {
                float ov = __shfl_xor(cv, off, 64);
                int   oi = __shfl_xor(ci, off, 64);
                if (ov > cv || (ov == cv && oi < ci)) { cv = ov; ci = oi; }
            }
            float ts = __shfl(s, ci, 64);      // unbiased score of winner
            sum += ts;
            if (lane == k)  { outv = ts; outi = ci; }
            if (lane == ci) { myv = -1e30f; }
        }
        const float denom = sum + 1e-20f;
        if (lane < TOPK) {
            out[(size_t)tok * TOPK + lane] = (outv / denom) * ROUTE_SCALE;
            out[(size_t)NTOK * TOPK + (size_t)tok * TOPK + lane] = (float)outi;
            atomicAdd(&hist[outi], 1);
        }
    }

    __syncthreads();
    if (t < NE) {
        int c = hist[t];
        if (c) atomicAdd(&out[(size_t)NTOK * TOPK * 2 + t], (float)c);
    }
}

extern "C" void kernel_launch(void* const* d_in, const int* in_sizes, int n_in,
                              void* d_out, int out_size, void* d_ws, size_t ws_size,
                              hipStream_t stream)
{
    const float* x    = (const float*)d_in[0];
    const float* gw   = (const float*)d_in[1];
    const float* bias = (const float*)d_in[2];
    float* out  = (float*)d_out;
    uint4* wS   = (uint4*)d_ws;
    float* part = (float*)((char*)d_ws + WS_PART_OFF);

    // histogram region must start at zero every call
    hipMemsetAsync(out + (size_t)NTOK * TOPK * 2, 0, NE * sizeof(float), stream);

    prep_w<<<128, 256, 0, stream>>>(gw, wS);
    gemm_stage<<<dim3(NTOK / 64, SPLITK), 64, 0, stream>>>(x, wS, part);
    epilogue<<<NTOK / 16, 256, 0, stream>>>(part, bias, out);
}

// Round 6
// 115.492 us; speedup vs baseline: 9.0299x; 1.1237x over previous
//
#include <hip/hip_runtime.h>
#include <math.h>

#define NTOK 16384
#define DIM  4096
#define NE   64
#define TOPK 8
#define SPLITK 8
#define NSLICE (DIM / SPLITK / 32)   // 16 k32-slices per wave
#define ROUTE_SCALE 2.5f

typedef __attribute__((ext_vector_type(8))) short short8v;
typedef __attribute__((ext_vector_type(4))) float f32x4;

// exact 3-term bf16 truncation split of 8 f32, packed as 3x short8 (bf16) frags
__device__ __forceinline__ void split3_pack(const float* v, uint4& b0, uint4& b1, uint4& b2)
{
    uint p0[8], p1[8], p2[8];
#pragma unroll
    for (int j = 0; j < 8; ++j) {
        const float xv = v[j];
        const uint  u0 = __float_as_uint(xv) & 0xffff0000u;
        const float f0 = __uint_as_float(u0);
        const float r  = xv - f0;                       // exact
        const uint  u1 = __float_as_uint(r) & 0xffff0000u;
        const float f1 = __uint_as_float(u1);
        const float r2 = r - f1;                        // exact, fits bf16
        const uint  u2 = __float_as_uint(r2) & 0xffff0000u;
        p0[j] = u0; p1[j] = u1; p2[j] = u2;
    }
    b0 = make_uint4(p0[1] | (p0[0] >> 16), p0[3] | (p0[2] >> 16),
                    p0[5] | (p0[4] >> 16), p0[7] | (p0[6] >> 16));
    b1 = make_uint4(p1[1] | (p1[0] >> 16), p1[3] | (p1[2] >> 16),
                    p1[5] | (p1[4] >> 16), p1[7] | (p1[6] >> 16));
    b2 = make_uint4(p2[1] | (p2[0] >> 16), p2[3] | (p2[2] >> 16),
                    p2[5] | (p2[4] >> 16), p2[7] | (p2[6] >> 16));
}

// ---- prep: w -> frag-ready bf16 splits. entry(ks,nt,sp,lane) at (ks*12 + nt*3+sp)*64+lane
__global__ __launch_bounds__(256)
void prep_w(const float* __restrict__ gw, uint4* __restrict__ wS)
{
    const int tid  = blockIdx.x * 256 + threadIdx.x;   // 32768 total
    const int lane = tid & 63;
    const int nt   = (tid >> 6) & 3;
    const int ks   = tid >> 8;                         // 0..127
    const int e    = nt * 16 + (lane & 15);
    const int kb   = ks * 32 + (lane >> 4) * 8;
    float v[8];
    *(float4*)&v[0] = *(const float4*)&gw[(size_t)e * DIM + kb];
    *(float4*)&v[4] = *(const float4*)&gw[(size_t)e * DIM + kb + 4];
    uint4 b0, b1, b2;
    split3_pack(v, b0, b1, b2);
    const size_t base = (size_t)(ks * 4 + nt) * 3 * 64 + lane;
    wS[base] = b0; wS[base + 64] = b1; wS[base + 128] = b2;
}

// ---- fused: 8-wave WG, wave==kh, 64 tokens/WG; gemm -> LDS partials -> top-8 ----
__global__ __launch_bounds__(512, 2)
void router_fused(const float* __restrict__ x, const uint4* __restrict__ wS,
                  const float* __restrict__ bias, float* __restrict__ out)
{
    __shared__ float part_lds[SPLITK][64][NE];   // 128 KB
    __shared__ int   hist[NE];

    const int t    = threadIdx.x;
    const int lane = t & 63;
    const int wv   = __builtin_amdgcn_readfirstlane(t >> 6);   // wave == kh, 0..7
    const int r    = lane & 15;
    const int g    = lane >> 4;
    const int tok0 = blockIdx.x * 64;
    const int ks0  = wv * NSLICE;              // global k32-slice base

    if (t < NE) hist[t] = 0;

    const float* xr[4];
#pragma unroll
    for (int G = 0; G < 4; ++G)
        xr[G] = x + (size_t)(tok0 + G * 16 + r) * DIM + ks0 * 32 + g * 8;
    const uint4* wB = wS + lane;

    f32x4 acc[16];                              // [nt*4 + G]
#pragma unroll
    for (int i = 0; i < 16; ++i) acc[i] = (f32x4){0.f, 0.f, 0.f, 0.f};

    float xP[32], xQ[32];                       // 4 groups x 8 floats
    uint4 bP[12], bQ[12];

#define LOADX(X, s) do {                                                     \
        _Pragma("unroll")                                                    \
        for (int G = 0; G < 4; ++G) {                                        \
            *(float4*)&X[G * 8]     = *(const float4*)(xr[G] + (size_t)(s) * 32);     \
            *(float4*)&X[G * 8 + 4] = *(const float4*)(xr[G] + (size_t)(s) * 32 + 4); \
        }                                                                    \
    } while (0)
#define LOADB(B, s) do {                                                     \
        _Pragma("unroll")                                                    \
        for (int i = 0; i < 12; ++i)                                         \
            B[i] = wB[((size_t)(ks0 + (s)) * 12 + i) * 64];                  \
    } while (0)
#define COMPUTE(X, B) do {                                                            \
        _Pragma("unroll")                                                             \
        for (int G = 0; G < 4; ++G) {                                                 \
            uint4 a0u, a1u, a2u;                                                      \
            split3_pack(&X[G * 8], a0u, a1u, a2u);                                    \
            const short8v a0 = *(short8v*)&a0u;                                       \
            const short8v a1 = *(short8v*)&a1u;                                       \
            const short8v a2 = *(short8v*)&a2u;                                       \
            _Pragma("unroll")                                                         \
            for (int nt = 0; nt < 4; ++nt) {                                          \
                const short8v b0 = *(const short8v*)&B[nt * 3 + 0];                   \
                const short8v b1 = *(const short8v*)&B[nt * 3 + 1];                   \
                const short8v b2 = *(const short8v*)&B[nt * 3 + 2];                   \
                f32x4 c = acc[nt * 4 + G];                                            \
                c = __builtin_amdgcn_mfma_f32_16x16x32_bf16(a2, b0, c, 0, 0, 0);      \
                c = __builtin_amdgcn_mfma_f32_16x16x32_bf16(a1, b1, c, 0, 0, 0);      \
                c = __builtin_amdgcn_mfma_f32_16x16x32_bf16(a0, b2, c, 0, 0, 0);      \
                c = __builtin_amdgcn_mfma_f32_16x16x32_bf16(a1, b0, c, 0, 0, 0);      \
                c = __builtin_amdgcn_mfma_f32_16x16x32_bf16(a0, b1, c, 0, 0, 0);      \
                c = __builtin_amdgcn_mfma_f32_16x16x32_bf16(a0, b0, c, 0, 0, 0);      \
                acc[nt * 4 + G] = c;                                                  \
            }                                                                         \
        }                                                                             \
    } while (0)

    LOADX(xP, 0);
    LOADB(bP, 0);
    for (int it = 0; it < NSLICE / 2; ++it) {
        const int s = 2 * it;
        LOADX(xQ, s + 1);
        LOADB(bQ, s + 1);
        COMPUTE(xP, bP);
        const int s2 = (s + 2) & (NSLICE - 1);   // last iter wraps to 0, never used
        LOADX(xP, s2);
        LOADB(bP, s2);
        COMPUTE(xQ, bQ);
    }
#undef LOADX
#undef LOADB
#undef COMPUTE

    // C/D layout (proven rounds 4-5): col = lane&15 (expert), row = g*4+q (token)
#pragma unroll
    for (int nt = 0; nt < 4; ++nt)
#pragma unroll
        for (int G = 0; G < 4; ++G)
#pragma unroll
            for (int q = 0; q < 4; ++q)
                part_lds[wv][G * 16 + g * 4 + q][nt * 16 + r] = acc[nt * 4 + G][q];

    __syncthreads();

    // ---- epilogue: 8 tokens per wave; lane == expert ----
    const float bias_l = bias[lane];
#pragma unroll 1
    for (int i = 0; i < 8; ++i) {
        const int tok = wv * 8 + i;
        float logit = 0.f;
#pragma unroll
        for (int kh = 0; kh < SPLITK; ++kh)     // fixed ascending order: bit-identical to round 5
            logit += part_lds[kh][tok][lane];
        const float s = 1.f / (1.f + expf(-logit));
        float myv  = s + bias_l;
        float outv = 0.f;
        int   outi = 0;
        float sum  = 0.f;
#pragma unroll
        for (int k = 0; k < TOPK; ++k) {
            float cv = myv;
            int   ci = lane;
#pragma unroll
            for (int off = 32; off; off >>= 1) {
                float ov = __shfl_xor(cv, off, 64);
                int   oi = __shfl_xor(ci, off, 64);
                if (ov > cv || (ov == cv && oi < ci)) { cv = ov; ci = oi; }
            }
            float ts = __shfl(s, ci, 64);      // unbiased score of winner
            sum += ts;
            if (lane == k)  { outv = ts; outi = ci; }
            if (lane == ci) { myv = -1e30f; }
        }
        const float denom = sum + 1e-20f;
        const size_t gt = (size_t)tok0 + tok;
        if (lane < TOPK) {
            out[gt * TOPK + lane] = (outv / denom) * ROUTE_SCALE;
            out[(size_t)NTOK * TOPK + gt * TOPK + lane] = (float)outi;
            atomicAdd(&hist[outi], 1);
        }
    }

    __syncthreads();
    if (t < NE) {
        int c = hist[t];
        if (c) atomicAdd(&out[(size_t)NTOK * TOPK * 2 + t], (float)c);
    }
}

extern "C" void kernel_launch(void* const* d_in, const int* in_sizes, int n_in,
                              void* d_out, int out_size, void* d_ws, size_t ws_size,
                              hipStream_t stream)
{
    const float* x    = (const float*)d_in[0];
    const float* gw   = (const float*)d_in[1];
    const float* bias = (const float*)d_in[2];
    float* out = (float*)d_out;
    uint4* wS  = (uint4*)d_ws;   // 1.5 MB

    // histogram region must start at zero every call
    hipMemsetAsync(out + (size_t)NTOK * TOPK * 2, 0, NE * sizeof(float), stream);

    prep_w<<<128, 256, 0, stream>>>(gw, wS);
    router_fused<<<NTOK / 64, 512, 0, stream>>>(x, wS, bias, out);
}